// Round 3
// baseline (947.889 us; speedup 1.0000x reference)
//
#include <hip/hip_runtime.h>
#include <hip/hip_bf16.h>
#include <cstdint>

typedef __bf16 bf16;
typedef __attribute__((ext_vector_type(4))) __bf16 bf16x4;
typedef __attribute__((ext_vector_type(8))) __bf16 bf16x8;
typedef __attribute__((ext_vector_type(4))) float f32x4;

#define AS1 __attribute__((address_space(1)))
#define AS3 __attribute__((address_space(3)))

__device__ __forceinline__ unsigned short f2bf(float x) {
    union { __bf16 b; unsigned short u; } c;
    c.b = (__bf16)x;
    return c.u;
}

// async global->LDS, 16B per lane. LDS dest = wave-uniform base + lane*16.
__device__ __forceinline__ void gld_lds16(const void* g, void* lds_wave_base) {
#if __has_builtin(__builtin_amdgcn_global_load_lds)
    __builtin_amdgcn_global_load_lds((AS1 void*)(uintptr_t)g,
                                     (AS3 void*)(uint32_t)(uintptr_t)lds_wave_base,
                                     16u, 0, 0u);
#else
    int lane = threadIdx.x & 63;
    *(uint4*)((char*)lds_wave_base + lane * 16) = *(const uint4*)g;
#endif
}

// ---------------- fp32 -> bf16 elementwise ----------------
__global__ __launch_bounds__(256) void cvt_kernel(const float* __restrict__ in,
                                                  bf16* __restrict__ out) {
    int i = (blockIdx.x * 256 + threadIdx.x) * 4;
    float4 v = *(const float4*)&in[i];
    bf16x4 o;
    o[0] = (__bf16)v.x; o[1] = (__bf16)v.y; o[2] = (__bf16)v.z; o[3] = (__bf16)v.w;
    *(bf16x4*)&out[i] = o;
}

// ---------------- fp32 [k][n] -> bf16 out[n][k] transpose+convert, n = 4096 ----------------
__global__ __launch_bounds__(256) void cvt_transpose_kernel(const float* __restrict__ in,
                                                            unsigned short* __restrict__ out, int n) {
    __shared__ unsigned short tile[64][65];
    int t = threadIdx.x;
    int n0 = blockIdx.x * 64, k0 = blockIdx.y * 64;
#pragma unroll
    for (int i = 0; i < 4; i++) {
        int idx = t + i * 256;
        int r = idx >> 4, cc = (idx & 15) * 4;
        float4 v = *(const float4*)&in[(size_t)(k0 + r) * n + n0 + cc];
        tile[r][cc + 0] = f2bf(v.x); tile[r][cc + 1] = f2bf(v.y);
        tile[r][cc + 2] = f2bf(v.z); tile[r][cc + 3] = f2bf(v.w);
    }
    __syncthreads();
#pragma unroll
    for (int i = 0; i < 4; i++) {
        int idx = t + i * 256;
        int nn = idx >> 4, kc = (idx & 15) * 4;
        ushort4 v;
        v.x = tile[kc + 0][nn]; v.y = tile[kc + 1][nn];
        v.z = tile[kc + 2][nn]; v.w = tile[kc + 3][nn];
        *(ushort4*)&out[(size_t)(n0 + nn) * n + k0 + kc] = v;
    }
}

// ---------------- bf16 transpose: out[n][k] = in[k][n], n = 4096 ----------------
__global__ __launch_bounds__(256) void transpose_bf16_kernel(const unsigned short* __restrict__ in,
                                                             unsigned short* __restrict__ out, int n) {
    __shared__ unsigned short tile[64][65];
    int t = threadIdx.x;
    int n0 = blockIdx.x * 64, k0 = blockIdx.y * 64;
#pragma unroll
    for (int i = 0; i < 4; i++) {
        int idx = t + i * 256;
        int r = idx >> 4, cc = (idx & 15) * 4;
        ushort4 v = *(const ushort4*)&in[(size_t)(k0 + r) * n + n0 + cc];
        tile[r][cc + 0] = v.x; tile[r][cc + 1] = v.y;
        tile[r][cc + 2] = v.z; tile[r][cc + 3] = v.w;
    }
    __syncthreads();
#pragma unroll
    for (int i = 0; i < 4; i++) {
        int idx = t + i * 256;
        int nn = idx >> 4, kc = (idx & 15) * 4;
        ushort4 v;
        v.x = tile[kc + 0][nn]; v.y = tile[kc + 1][nn];
        v.z = tile[kc + 2][nn]; v.w = tile[kc + 3][nn];
        *(ushort4*)&out[(size_t)(n0 + nn) * n + k0 + kc] = v;
    }
}

// ================= 256x256 ring-pipelined GEMM: C[m,n] = sum_k A[m,k]*BT[n,k] + bias[n] =============
// MODE 0: write bf16 C, no residual. MODE 1: write fp32 C, add bf16 residual.
//
// LDS: ring of 5 half-tile sub-arrays per operand (10 x 16KB = 160 KB, full CU LDS).
// Each sub-array: [128 lines][128B] holding 256 rows x 32 k as row-pairs per line,
// XOR-swizzled phys_slot = log_slot ^ (line&7); staging writes LDS linearly with the
// swizzle applied to the per-lane GLOBAL source (both-sides involution) -> 0 bank conflicts.
//
// Half h (k columns [32h,32h+32)) lives in slot h%5. Ring depth 5 gives WAR distance:
// staging h (during tile t = (h-3)>>1 or (h-4)>>1) overwrites h-5, whose reads completed
// before barrier(t-1). => ONE barrier per K-tile (after lgkmcnt(0) + counted vmcnt(4)).
// Between barriers each wave is fully independent: frag ds_reads issue one phase ahead of
// their MFMA cluster, and waves drift within the tile so LDS and MFMA pipes overlap
// (round-2 bug: a mid-tile barrier re-locked all waves -> pipes serialized, MfmaUtil 44%).
//
// vmcnt audit (per wave, 2 gld_lds ops per stage): prologue stages h=0,1,2 (12 ops),
// vmcnt(4) leaves h=2's 4 ops in flight. Steady tile t stages h=2t+3 (P1,P2), h=2t+4
// (P3,P4); at P4 vmcnt(4) drains everything through h=2t+3 leaving h=2t+4's 4 ops.
// Tail: t >= nT-2 uses vmcnt(0).

__device__ __forceinline__ void stage_khalf(const bf16* __restrict__ gb, int ldk, int kcol0,
                                            bf16* dst /*16KB sub-array*/) {
    const int t = threadIdx.x;
    const int wave = t >> 6;
#pragma unroll
    for (int i = 0; i < 2; i++) {
        int idx = i * 512 + t;          // 16B unit index 0..1023
        int line = idx >> 3;
        int slot = (idx & 7) ^ (line & 7);
        int row = line * 2 + (slot >> 2);
        int kc = (slot & 3) * 8;
        gld_lds16(gb + (size_t)row * ldk + kcol0 + kc,
                  dst + (size_t)(i * 512 + wave * 64) * 8);
    }
}

__device__ __forceinline__ bf16x8 frag_ld(const bf16* sub, int r, int lq) {
    int line = r >> 1;
    int slot = (((r & 1) << 2) | lq) ^ (line & 7);
    return *(const bf16x8*)((const char*)sub + line * 128 + slot * 16);
}

template <int MODE>
__global__ __launch_bounds__(512, 2) void gemm256_kernel(
    const bf16* __restrict__ A, const bf16* __restrict__ BT,
    const float* __restrict__ bias, const bf16* __restrict__ resid,
    void* __restrict__ Cout, int M, int N, int K) {
    __shared__ __align__(16) bf16 lds[81920];  // 160 KiB: 5 x 16KB A-ring + 5 x 16KB B-ring
    const int tid = threadIdx.x;
    const int wave = tid >> 6, lane = tid & 63;
    const int lq = lane >> 4, lm = lane & 15;
    const int wr = wave >> 2, wcq = wave & 3;  // 2M x 4N waves

    // XCD-aware swizzle (gridDim.x multiple of 8)
    const int nwg = gridDim.x;
    const int chunk = nwg >> 3;
    const int bid = blockIdx.x;
    const int swz = (bid & 7) * chunk + (bid >> 3);
    const unsigned nbn = (unsigned)(N >> 8);
    const int bm = (int)((unsigned)swz / nbn);
    const int bn = (int)((unsigned)swz % nbn);
    const int row0 = bm << 8, col0 = bn << 8;

    const bf16* Ag = A + (size_t)row0 * K;
    const bf16* Bg = BT + (size_t)col0 * K;
    const int nT = K >> 6;

#define SUBA(h) (lds + (size_t)((h) % 5) * 8192)
#define SUBB(h) (lds + 40960 + (size_t)((h) % 5) * 8192)

    f32x4 acc[8][4];
#pragma unroll
    for (int i = 0; i < 8; i++)
#pragma unroll
        for (int j = 0; j < 4; j++) acc[i][j] = (f32x4){0.f, 0.f, 0.f, 0.f};

    // ---- prologue: stage halves 0,1,2; drain 0,1 (leave 2's 4 ops in flight) ----
    stage_khalf(Ag, K, 0, SUBA(0));
    stage_khalf(Bg, K, 0, SUBB(0));
    stage_khalf(Ag, K, 32, SUBA(1));
    stage_khalf(Bg, K, 32, SUBB(1));
    stage_khalf(Ag, K, 64, SUBA(2));
    stage_khalf(Bg, K, 64, SUBB(2));
    asm volatile("s_waitcnt vmcnt(4)" ::: "memory");
    __builtin_amdgcn_s_barrier();

    const int arow = wr * 128 + lm;   // + mt*16 (+64 for upper half)
    const int brow = wcq * 64 + lm;   // + nt*16

    // initial frag prefetch from half 0
    bf16x8 a0[4], a1[4], b0[4], b1[4];
#pragma unroll
    for (int i = 0; i < 4; i++) a0[i] = frag_ld(SUBA(0), arow + i * 16, lq);
#pragma unroll
    for (int j = 0; j < 4; j++) b0[j] = frag_ld(SUBB(0), brow + j * 16, lq);

    for (int t = 0; t < nT; ++t) {
        const bf16* Ak0 = SUBA(2 * t);
        const bf16* Ak1 = SUBA(2 * t + 1);
        const bf16* Bk1 = SUBB(2 * t + 1);

        // ---- P1: prefetch a1 (k0 hi-rows); stage A-half(2t+3); MFMA a0 x b0 ----
#pragma unroll
        for (int i = 0; i < 4; i++) a1[i] = frag_ld(Ak0, arow + 64 + i * 16, lq);
        if (t < nT - 1) stage_khalf(Ag, K, (2 * t + 3) * 32, SUBA(2 * t + 3));
        __builtin_amdgcn_s_setprio(1);
#pragma unroll
        for (int i = 0; i < 4; i++)
#pragma unroll
            for (int j = 0; j < 4; j++)
                acc[i][j] = __builtin_amdgcn_mfma_f32_16x16x32_bf16(a0[i], b0[j], acc[i][j], 0, 0, 0);
        __builtin_amdgcn_s_setprio(0);

        // ---- P2: prefetch a0<-k1 lo, b1<-k1; stage B-half(2t+3); MFMA a1 x b0 ----
#pragma unroll
        for (int i = 0; i < 4; i++) a0[i] = frag_ld(Ak1, arow + i * 16, lq);
#pragma unroll
        for (int j = 0; j < 4; j++) b1[j] = frag_ld(Bk1, brow + j * 16, lq);
        if (t < nT - 1) stage_khalf(Bg, K, (2 * t + 3) * 32, SUBB(2 * t + 3));
        __builtin_amdgcn_s_setprio(1);
#pragma unroll
        for (int i = 0; i < 4; i++)
#pragma unroll
            for (int j = 0; j < 4; j++)
                acc[4 + i][j] = __builtin_amdgcn_mfma_f32_16x16x32_bf16(a1[i], b0[j], acc[4 + i][j], 0, 0, 0);
        __builtin_amdgcn_s_setprio(0);

        // ---- P3: prefetch a1<-k1 hi; stage A-half(2t+4); MFMA a0 x b1 ----
#pragma unroll
        for (int i = 0; i < 4; i++) a1[i] = frag_ld(Ak1, arow + 64 + i * 16, lq);
        if (t < nT - 2) stage_khalf(Ag, K, (2 * t + 4) * 32, SUBA(2 * t + 4));
        __builtin_amdgcn_s_setprio(1);
#pragma unroll
        for (int i = 0; i < 4; i++)
#pragma unroll
            for (int j = 0; j < 4; j++)
                acc[i][j] = __builtin_amdgcn_mfma_f32_16x16x32_bf16(a0[i], b1[j], acc[i][j], 0, 0, 0);
        __builtin_amdgcn_s_setprio(0);

        // ---- P4: stage B-half(2t+4); drain own reads (WAR) + counted vmcnt (RAW for
        //          halves 2t+2,2t+3); single barrier; prefetch next tile's a0,b0; MFMA a1 x b1 ----
        if (t < nT - 2) stage_khalf(Bg, K, (2 * t + 4) * 32, SUBB(2 * t + 4));
        asm volatile("s_waitcnt lgkmcnt(0)" ::: "memory");
        if (t < nT - 2) {
            asm volatile("s_waitcnt vmcnt(4)" ::: "memory");
        } else {
            asm volatile("s_waitcnt vmcnt(0)" ::: "memory");
        }
        __builtin_amdgcn_s_barrier();
        if (t + 1 < nT) {
            const bf16* An = SUBA(2 * t + 2);
            const bf16* Bn = SUBB(2 * t + 2);
#pragma unroll
            for (int i = 0; i < 4; i++) a0[i] = frag_ld(An, arow + i * 16, lq);
#pragma unroll
            for (int j = 0; j < 4; j++) b0[j] = frag_ld(Bn, brow + j * 16, lq);
        }
        __builtin_amdgcn_s_setprio(1);
#pragma unroll
        for (int i = 0; i < 4; i++)
#pragma unroll
            for (int j = 0; j < 4; j++)
                acc[4 + i][j] = __builtin_amdgcn_mfma_f32_16x16x32_bf16(a1[i], b1[j], acc[4 + i][j], 0, 0, 0);
        __builtin_amdgcn_s_setprio(0);
    }
#undef SUBA
#undef SUBB

    // epilogue: C/D layout col = lane&15, row = (lane>>4)*4 + reg
#pragma unroll
    for (int nt = 0; nt < 4; nt++) {
        int col = col0 + wcq * 64 + nt * 16 + lm;
        float bv = bias[col];
#pragma unroll
        for (int mt = 0; mt < 8; mt++) {
            int rbase = row0 + wr * 128 + mt * 16 + lq * 4;
#pragma unroll
            for (int r = 0; r < 4; r++) {
                int row = rbase + r;
                float v = acc[mt][nt][r] + bv;
                if (MODE == 0) {
                    ((bf16*)Cout)[(size_t)row * N + col] = (bf16)v;
                } else {
                    v += (float)resid[(size_t)row * N + col];
                    ((float*)Cout)[(size_t)row * N + col] = v;
                }
            }
        }
    }
}

// ---------------- MFMA block-diagonal flash attention + residual ----------------
// grid: (nseg*8, 18). block = (seg, head, 64-row i-tile), 4 waves, 16 Q-rows/wave.
// Q in register A-frags; K tile row-major LDS; V^T tile (pre-transposed global) LDS.
__global__ __launch_bounds__(256, 2) void attn_kernel(
    const bf16* __restrict__ Q, const bf16* __restrict__ K, const bf16* __restrict__ Vt,
    const int* __restrict__ num_rels, const float* __restrict__ X,
    bf16* __restrict__ R1) {
    const float SCALE = 0.044194173824159216f;  // 1/sqrt(512)
    int seg = blockIdx.x >> 3;
    int h = blockIdx.x & 7;
    int S = 0;
    for (int i = 0; i < seg; i++) S += num_rels[i];
    int L = num_rels[seg];
    int i0 = blockIdx.y * 64;
    if (i0 >= L) return;

    __shared__ __align__(16) bf16 Ks[32][520];    // K tile, +8 pad -> conflict-free frags
    __shared__ __align__(16) bf16 Vs[512][40];    // V^T tile, +8 pad
    __shared__ __align__(16) bf16 Ps[4][16][40];  // per-wave P tile (C-layout -> A-layout)

    const int t = threadIdx.x;
    const int wave = t >> 6, lane = t & 63;
    const int lq = lane >> 4, lm = lane & 15;

    // Q rows for this wave, held as 16 A-fragments (row = lm, k-chunk c)
    const int qrow = i0 + wave * 16 + lm;
    const bool qvalid = qrow < L;
    bf16x8 aq[16];
    {
        const bf16* qb = Q + (size_t)(S + qrow) * 4096 + h * 512 + lq * 8;
#pragma unroll
        for (int c = 0; c < 16; c++) {
            bf16x8 v = {};
            if (qvalid) v = *(const bf16x8*)(qb + c * 32);
            aq[c] = v;
        }
    }

    f32x4 accO[32];
#pragma unroll
    for (int i = 0; i < 32; i++) accO[i] = (f32x4){0.f, 0.f, 0.f, 0.f};
    float m_r[4], l_r[4];
#pragma unroll
    for (int r = 0; r < 4; r++) { m_r[r] = -1e30f; l_r[r] = 0.f; }

    for (int j0 = 0; j0 < L; j0 += 32) {
        // stage K tile [32][512] (coalesced; rows past L hold neighboring data -> masked later)
#pragma unroll
        for (int it = 0; it < 8; it++) {
            int c = t + it * 256;
            int r = c >> 6, cc = (c & 63) * 8;
            *(uint4*)&Ks[r][cc] = *(const uint4*)&K[(size_t)(S + j0 + r) * 4096 + h * 512 + cc];
        }
        // stage V^T tile [512][32]
#pragma unroll
        for (int it = 0; it < 8; it++) {
            int c = t + it * 256;
            int r = c >> 2, cc = (c & 3) * 8;
            *(uint4*)&Vs[r][cc] = *(const uint4*)&Vt[(size_t)(h * 512 + r) * 4096 + S + j0 + cc];
        }
        __syncthreads();

        // S = Q K^T : 2 col-subtiles x 16 k-chunks
        f32x4 accS[2];
        accS[0] = (f32x4){0.f, 0.f, 0.f, 0.f};
        accS[1] = (f32x4){0.f, 0.f, 0.f, 0.f};
#pragma unroll
        for (int ct = 0; ct < 2; ct++)
#pragma unroll
            for (int c = 0; c < 16; c++) {
                bf16x8 bk = *(const bf16x8*)&Ks[ct * 16 + lm][c * 32 + lq * 8];
                accS[ct] = __builtin_amdgcn_mfma_f32_16x16x32_bf16(aq[c], bk, accS[ct], 0, 0, 0);
            }

        // online softmax; row i = lq*4 + r (C-layout), col j = j0 + ct*16 + lm
        bool v0 = (j0 + lm) < L, v1 = (j0 + 16 + lm) < L;
        float p0v[4], p1v[4], alpha[4];
#pragma unroll
        for (int r = 0; r < 4; r++) {
            float s0 = v0 ? accS[0][r] * SCALE : -1e30f;
            float s1 = v1 ? accS[1][r] * SCALE : -1e30f;
            float mx = fmaxf(s0, s1);
#pragma unroll
            for (int o = 1; o < 16; o <<= 1) mx = fmaxf(mx, __shfl_xor(mx, o, 64));
            float mnew = fmaxf(m_r[r], mx);
            alpha[r] = __expf(m_r[r] - mnew);
            float p0 = __expf(s0 - mnew), p1 = __expf(s1 - mnew);
            float sum = p0 + p1;
#pragma unroll
            for (int o = 1; o < 16; o <<= 1) sum += __shfl_xor(sum, o, 64);
            l_r[r] = l_r[r] * alpha[r] + sum;
            m_r[r] = mnew;
            p0v[r] = p0; p1v[r] = p1;
        }
        // write P to per-wave LDS tile (C-layout -> A-layout round trip)
#pragma unroll
        for (int r = 0; r < 4; r++) {
            Ps[wave][lq * 4 + r][lm] = (bf16)p0v[r];
            Ps[wave][lq * 4 + r][16 + lm] = (bf16)p1v[r];
        }
        // rescale O
#pragma unroll
        for (int i = 0; i < 32; i++)
#pragma unroll
            for (int r = 0; r < 4; r++) accO[i][r] *= alpha[r];

        // O += P V : A-frag from Ps (same wave; in-order LDS), B-frags from V^T tile
        bf16x8 ap = *(const bf16x8*)&Ps[wave][lm][lq * 8];
#pragma unroll
        for (int ct2 = 0; ct2 < 32; ct2++) {
            bf16x8 bv = *(const bf16x8*)&Vs[ct2 * 16 + lm][lq * 8];
            accO[ct2] = __builtin_amdgcn_mfma_f32_16x16x32_bf16(ap, bv, accO[ct2], 0, 0, 0);
        }
        __syncthreads();
    }

    // epilogue: row = i0 + wave*16 + lq*4 + r, col = ct2*16 + lm
#pragma unroll
    for (int r = 0; r < 4; r++) {
        int row = i0 + wave * 16 + lq * 4 + r;
        if (row >= L) continue;
        float inv = 1.f / l_r[r];
        size_t base = (size_t)(S + row) * 4096 + h * 512;
#pragma unroll
        for (int ct2 = 0; ct2 < 32; ct2++) {
            int col = ct2 * 16 + lm;
            R1[base + col] = (bf16)(accO[ct2][r] * inv + X[base + col]);
        }
    }
}

extern "C" void kernel_launch(void* const* d_in, const int* in_sizes, int n_in,
                              void* d_out, int out_size, void* d_ws, size_t ws_size,
                              hipStream_t stream) {
    const float* prod = (const float*)d_in[0];
    const int* nr = (const int*)d_in[1];
    const float* Wq = (const float*)d_in[2];
    const float* bq = (const float*)d_in[3];
    const float* Wk = (const float*)d_in[4];
    const float* bk = (const float*)d_in[5];
    const float* Wv = (const float*)d_in[6];
    const float* bv = (const float*)d_in[7];
    const float* Wfc = (const float*)d_in[8];
    const float* bfc = (const float*)d_in[9];
    float* out = (float*)d_out;

    const size_t MATB = (size_t)4096 * 4096 * sizeof(bf16);  // 33.55 MB
    char* ws = (char*)d_ws;
    bf16* Xb = (bf16*)(ws + 0 * MATB);   // bf16 prod_rep; later reused as V^T
    bf16* Qb = (bf16*)(ws + 1 * MATB);   // later reused as res1
    bf16* Kb = (bf16*)(ws + 2 * MATB);
    bf16* Vb = (bf16*)(ws + 3 * MATB);
    bf16* WT = (bf16*)(ws + 4 * MATB);   // reused per weight transpose

    int nseg = in_sizes[1];

    dim3 cb(256), cg(16384);
    dim3 tb(256), tg(64, 64);
    dim3 gb(512), gg(256);               // 256x256 tiles: (4096/256)^2 blocks, 1 per CU

    cvt_kernel<<<cg, cb, 0, stream>>>(prod, Xb);

    cvt_transpose_kernel<<<tg, tb, 0, stream>>>(Wq, (unsigned short*)WT, 4096);
    gemm256_kernel<0><<<gg, gb, 0, stream>>>(Xb, WT, bq, nullptr, Qb, 4096, 4096, 4096);
    cvt_transpose_kernel<<<tg, tb, 0, stream>>>(Wk, (unsigned short*)WT, 4096);
    gemm256_kernel<0><<<gg, gb, 0, stream>>>(Xb, WT, bk, nullptr, Kb, 4096, 4096, 4096);
    cvt_transpose_kernel<<<tg, tb, 0, stream>>>(Wv, (unsigned short*)WT, 4096);
    gemm256_kernel<0><<<gg, gb, 0, stream>>>(Xb, WT, bv, nullptr, Vb, 4096, 4096, 4096);

    // V^T into the freed Xb slot
    transpose_bf16_kernel<<<tg, tb, 0, stream>>>((const unsigned short*)Vb, (unsigned short*)Xb, 4096);

    dim3 ab(256), ag(nseg * 8, 18);  // 18 * 64 >= Lmax = 1120
    attn_kernel<<<ag, ab, 0, stream>>>(Qb, Kb, Xb, nr, prod, Qb);

    cvt_transpose_kernel<<<tg, tb, 0, stream>>>(Wfc, (unsigned short*)WT, 4096);
    gemm256_kernel<1><<<gg, gb, 0, stream>>>(Qb, WT, bfc, Qb, out, 4096, 4096, 4096);
}